// Round 4
// baseline (159.034 us; speedup 1.0000x reference)
//
#include <hip/hip_runtime.h>
#include <math.h>

// S4D kernel generation: K[h,l] = 2*Re( sum_n Ck[h,n] * exp(dtA[h,n]*l) )
// H=1024, N2=32, L=4096. Output (H,L) fp32.
//
// Three-level factorization: l = 256*j + 16*a + b  (j,a in [0,16), b in [0,16))
//   K[h,l] = Re( sum_n A2[n,j] * P[n,a] * Q[n,b] )
//   Q[n,b] = 2*Cc*(w-1)/A * w^b   (w = exp(dtA))
//   P[n,a] = (w^16)^a
//   A2[n,j] = (w^256)^j
// prep kernel: one thread per (h,n); all fp64 (exp/sin/cos, 8 squarings) plus
// 45 f32 complex muls; writes P,Q to ws region 1 and A2 transposed ([h][j][n])
// to ws region 2.
// main kernel: one block per h, 256 threads, t -> (a=t>>4, b=t&15).
//   Phase 1: stage P,Q (8 KB) to LDS, build B[n] = P[n,a]*Q[n,b] in regs
//            (LDS reads are broadcast / conflict-free by construction).
//   Phase 2: acc[j] += A2r*Br - A2i*Bi; A2 rows are wave-uniform -> scalar
//            loads on the scalar pipe. Pure f32 FMA, no transcendentals,
//            no fp64, no serial recurrences.

#define N2 32
#define L_LEN 4096
#define NTHREADS 256

// ws layout (in float2 units)
#define PQ_STRIDE 32                    // per (h,n): P[16] then Q[16]
#define A2OFF (1024 * 1024)             // float2s: H*N2*PQ_STRIDE = 1M float2 = 8 MB

__global__ __launch_bounds__(256) void s4d_prep_kernel(
    const float* __restrict__ log_dt,      // (H,)
    const float* __restrict__ Cri,         // (H, N2, 2)
    const float* __restrict__ log_A_real,  // (H, N2)
    const float* __restrict__ A_imag,      // (H, N2)
    float2* __restrict__ ws2)
{
  const int idx = blockIdx.x * 256 + threadIdx.x;   // h*N2 + n
  const int h = idx >> 5;
  const int n = idx & 31;

  const double dt = exp((double)log_dt[h]);
  const double Ar = -exp((double)log_A_real[idx]);
  const double Ai = (double)A_imag[idx];
  const double xr = dt * Ar;
  const double xi = dt * Ai;
  const double ex = exp(xr);
  const double wr = ex * cos(xi);     // w = exp(dtA)
  const double wi = ex * sin(xi);
  // Ck = 2 * Cc * (w-1)/A
  const double nr = wr - 1.0, ni = wi;
  const double inv = 1.0 / (Ar * Ar + Ai * Ai);
  const double fr = (nr * Ar + ni * Ai) * inv;
  const double fi = (ni * Ar - nr * Ai) * inv;
  const double c0 = (double)Cri[idx * 2 + 0];
  const double c1 = (double)Cri[idx * 2 + 1];
  const float ckr = (float)(2.0 * (c0 * fr - c1 * fi));
  const float cki = (float)(2.0 * (c0 * fi + c1 * fr));

  // w^16 and w^256 by squaring in fp64 (phase accuracy), then round to f32
  double ar = wr, ai2 = wi;
#pragma unroll
  for (int k = 0; k < 4; ++k) {
    const double tr = ar * ar - ai2 * ai2;
    const double ti = 2.0 * ar * ai2;
    ar = tr; ai2 = ti;
  }
  const float w16r = (float)ar, w16i = (float)ai2;
#pragma unroll
  for (int k = 0; k < 4; ++k) {
    const double tr = ar * ar - ai2 * ai2;
    const double ti = 2.0 * ar * ai2;
    ar = tr; ai2 = ti;
  }
  const float w256r = (float)ar, w256i = (float)ai2;
  const float wfr = (float)wr, wfi = (float)wi;

  float2* pq = ws2 + (size_t)idx * PQ_STRIDE;
  // P[a] = (w^16)^a
  float pr = 1.0f, pi = 0.0f;
#pragma unroll
  for (int a = 0; a < 16; ++a) {
    pq[a] = make_float2(pr, pi);
    const float tr = fmaf(pr, w16r, -(pi * w16i));
    const float ti = fmaf(pr, w16i, pi * w16r);
    pr = tr; pi = ti;
  }
  // Q[b] = Ck * w^b
  float qr = ckr, qi = cki;
#pragma unroll
  for (int b = 0; b < 16; ++b) {
    pq[16 + b] = make_float2(qr, qi);
    const float tr = fmaf(qr, wfr, -(qi * wfi));
    const float ti = fmaf(qr, wfi, qi * wfr);
    qr = tr; qi = ti;
  }
  // A2T[h][j][n] = (w^256)^j
  float2* a2 = ws2 + A2OFF + (size_t)h * (16 * N2) + n;
  float sr = 1.0f, si = 0.0f;
#pragma unroll
  for (int j = 0; j < 16; ++j) {
    a2[j * N2] = make_float2(sr, si);
    const float tr = fmaf(sr, w256r, -(si * w256i));
    const float ti = fmaf(sr, w256i, si * w256r);
    sr = tr; si = ti;
  }
}

__global__ __launch_bounds__(NTHREADS, 4) void s4d_main_kernel(
    const float2* __restrict__ ws2,
    float* __restrict__ out)               // (H, L)
{
  const int h = blockIdx.x;
  const int t = threadIdx.x;
  const int a = t >> 4;
  const int b = t & 15;

  // Stage this head's P,Q block (N2*PQ_STRIDE = 1024 float2 = 8 KB) into LDS.
  __shared__ float2 sPQ[N2 * PQ_STRIDE];
  {
    const float4* src = (const float4*)(ws2 + (size_t)h * N2 * PQ_STRIDE);
    float4* dst = (float4*)sPQ;
#pragma unroll
    for (int i = 0; i < 2; ++i) dst[t + i * NTHREADS] = src[t + i * NTHREADS];
  }
  __syncthreads();

  // Phase 1: B[n] = P[n,a] * Q[n,b]
  float br[N2], bi[N2];
#pragma unroll
  for (int n = 0; n < N2; ++n) {
    const float2 P = sPQ[n * PQ_STRIDE + a];
    const float2 Q = sPQ[n * PQ_STRIDE + 16 + b];
    br[n] = fmaf(P.x, Q.x, -(P.y * Q.y));
    bi[n] = fmaf(P.x, Q.y, P.y * Q.x);
  }

  // Phase 2: acc[j] = sum_n A2r[n,j]*Br[n] - A2i[n,j]*Bi[n]
  const float2* a2h = ws2 + A2OFF + (size_t)h * (16 * N2);  // [j][n], uniform
  float acc[16];
#pragma unroll 4
  for (int j = 0; j < 16; ++j) {
    const float2* row = a2h + j * N2;       // wave-uniform -> s_load
    float s = 0.0f;
#pragma unroll
    for (int n = 0; n < N2; ++n) {
      const float2 a2 = row[n];
      s = fmaf(a2.x, br[n], s);
      s = fmaf(-a2.y, bi[n], s);
    }
    acc[j] = s;
  }

  float* o = out + (size_t)h * L_LEN + t;   // l = 256*j + t, t = 16a+b
#pragma unroll
  for (int j = 0; j < 16; ++j) o[j * NTHREADS] = acc[j];
}

extern "C" void kernel_launch(void* const* d_in, const int* in_sizes, int n_in,
                              void* d_out, int out_size, void* d_ws, size_t ws_size,
                              hipStream_t stream) {
  const float* log_dt     = (const float*)d_in[0];
  const float* Cri        = (const float*)d_in[1];
  const float* log_A_real = (const float*)d_in[2];
  const float* A_imag     = (const float*)d_in[3];
  float* out = (float*)d_out;
  const int H = in_sizes[0];

  float2* ws2 = (float2*)d_ws;   // 8 MB P/Q + 4 MB A2T

  s4d_prep_kernel<<<dim3(H * N2 / 256), dim3(256), 0, stream>>>(
      log_dt, Cri, log_A_real, A_imag, ws2);
  s4d_main_kernel<<<dim3(H), dim3(NTHREADS), 0, stream>>>(ws2, out);
}

// Round 5
// 91.876 us; speedup vs baseline: 1.7310x; 1.7310x over previous
//
#include <hip/hip_runtime.h>
#include <math.h>

// S4D kernel generation: K[h,l] = 2*Re( sum_n Ck[h,n] * exp(dtA[h,n]*l) )
// H=1024, N2=32, L=4096. Output (H,L) fp32.
//
// Three-level factorization: l = 256*j + 16*a + b  (j in [0,16), a,b in [0,16))
//   K[h,l] = Re( sum_n A2[n,j] * P[n,a] * Q[n,b] )
//   Q[n,b] = 2*Cc*(w-1)/A * w^b   (w = exp(dtA));  P[n,a] = (w^16)^a;
//   A2[n,j] = (w^256)^j.
// prep: one thread per (h,n), all fp64; writes P,Q and A2^T ([h][j][n]) to ws.
// main: grid (H,2), 256 threads; block y owns j in [8y,8y+8); t -> (a,b).
//   All loops FULLY unrolled (R4 lesson: partial unroll -> dynamic array
//   index -> scratch spill -> 300 MB of HBM spill traffic). Modes processed
//   in 2 chunks of 16 so live regs stay ~40 floats. A2 addresses depend only
//   on blockIdx -> uniform -> scalar loads feeding SGPR-operand v_fma.

#define N2 32
#define L_LEN 4096
#define NTHREADS 256
#define JT 8

// ws layout (float2 units)
#define PQ_STRIDE 32                    // per (h,n): P[16] then Q[16]
#define A2OFF (1024 * 1024)             // H*N2*PQ_STRIDE float2 = 8 MB

__global__ __launch_bounds__(256) void s4d_prep_kernel(
    const float* __restrict__ log_dt,      // (H,)
    const float* __restrict__ Cri,         // (H, N2, 2)
    const float* __restrict__ log_A_real,  // (H, N2)
    const float* __restrict__ A_imag,      // (H, N2)
    float2* __restrict__ ws2)
{
  const int idx = blockIdx.x * 256 + threadIdx.x;   // h*N2 + n
  const int h = idx >> 5;
  const int n = idx & 31;

  const double dt = exp((double)log_dt[h]);
  const double Ar = -exp((double)log_A_real[idx]);
  const double Ai = (double)A_imag[idx];
  const double xr = dt * Ar;
  const double xi = dt * Ai;
  const double ex = exp(xr);
  const double wr = ex * cos(xi);     // w = exp(dtA)
  const double wi = ex * sin(xi);
  // Ck = 2 * Cc * (w-1)/A
  const double nr = wr - 1.0, ni = wi;
  const double inv = 1.0 / (Ar * Ar + Ai * Ai);
  const double fr = (nr * Ar + ni * Ai) * inv;
  const double fi = (ni * Ar - nr * Ai) * inv;
  const double c0 = (double)Cri[idx * 2 + 0];
  const double c1 = (double)Cri[idx * 2 + 1];
  const float ckr = (float)(2.0 * (c0 * fr - c1 * fi));
  const float cki = (float)(2.0 * (c0 * fi + c1 * fr));

  // w^16 and w^256 by fp64 squarings (phase accuracy), rounded to f32
  double ar = wr, ai2 = wi;
#pragma unroll
  for (int k = 0; k < 4; ++k) {
    const double tr = ar * ar - ai2 * ai2;
    const double ti = 2.0 * ar * ai2;
    ar = tr; ai2 = ti;
  }
  const float w16r = (float)ar, w16i = (float)ai2;
#pragma unroll
  for (int k = 0; k < 4; ++k) {
    const double tr = ar * ar - ai2 * ai2;
    const double ti = 2.0 * ar * ai2;
    ar = tr; ai2 = ti;
  }
  const float w256r = (float)ar, w256i = (float)ai2;
  const float wfr = (float)wr, wfi = (float)wi;

  float2* pq = ws2 + (size_t)idx * PQ_STRIDE;
  float pr = 1.0f, pi = 0.0f;
#pragma unroll
  for (int a = 0; a < 16; ++a) {           // P[a] = (w^16)^a
    pq[a] = make_float2(pr, pi);
    const float tr = fmaf(pr, w16r, -(pi * w16i));
    const float ti = fmaf(pr, w16i, pi * w16r);
    pr = tr; pi = ti;
  }
  float qr = ckr, qi = cki;
#pragma unroll
  for (int b = 0; b < 16; ++b) {           // Q[b] = Ck * w^b
    pq[16 + b] = make_float2(qr, qi);
    const float tr = fmaf(qr, wfr, -(qi * wfi));
    const float ti = fmaf(qr, wfi, qi * wfr);
    qr = tr; qi = ti;
  }
  float2* a2 = ws2 + A2OFF + (size_t)h * (16 * N2) + n;
  float sr = 1.0f, si = 0.0f;
#pragma unroll
  for (int j = 0; j < 16; ++j) {           // A2T[h][j][n] = (w^256)^j
    a2[j * N2] = make_float2(sr, si);
    const float tr = fmaf(sr, w256r, -(si * w256i));
    const float ti = fmaf(sr, w256i, si * w256r);
    sr = tr; si = ti;
  }
}

__global__ __launch_bounds__(NTHREADS) void s4d_main_kernel(
    const float2* __restrict__ ws2,
    float* __restrict__ out)               // (H, L)
{
  const int h = blockIdx.x;
  const int jbase = blockIdx.y * JT;       // 0 or 8
  const int t = threadIdx.x;
  const int a = t >> 4;
  const int b = t & 15;

  // Stage this head's P,Q block (1024 float2 = 8 KB) into LDS.
  __shared__ float2 sPQ[N2 * PQ_STRIDE];
  {
    const float4* src = (const float4*)(ws2 + (size_t)h * N2 * PQ_STRIDE);
    float4* dst = (float4*)sPQ;
    dst[t] = src[t];
    dst[t + NTHREADS] = src[t + NTHREADS];
  }
  __syncthreads();

  float acc[JT];
#pragma unroll
  for (int j = 0; j < JT; ++j) acc[j] = 0.0f;

  const float2* a2h = ws2 + A2OFF + ((size_t)h * 16 + jbase) * N2;  // uniform

#pragma unroll
  for (int c = 0; c < 2; ++c) {
    // B[m] = P[m,a] * Q[m,b] for this chunk of 16 modes (LDS broadcast reads)
    float br[16], bi[16];
#pragma unroll
    for (int n = 0; n < 16; ++n) {
      const int m = c * 16 + n;
      const float2 P = sPQ[m * PQ_STRIDE + a];
      const float2 Q = sPQ[m * PQ_STRIDE + 16 + b];
      br[n] = fmaf(P.x, Q.x, -(P.y * Q.y));
      bi[n] = fmaf(P.x, Q.y, P.y * Q.x);
    }
    // acc[j] += Re(A2[j,m] * B[m]); A2 reads are wave-uniform -> scalar pipe
#pragma unroll
    for (int j = 0; j < JT; ++j) {
      const float2* row = a2h + j * N2 + c * 16;
      float s = acc[j];
#pragma unroll
      for (int n = 0; n < 16; ++n) {
        const float2 w = row[n];
        s = fmaf(w.x, br[n], s);
        s = fmaf(-w.y, bi[n], s);
      }
      acc[j] = s;
    }
  }

  float* o = out + (size_t)h * L_LEN + jbase * NTHREADS + t;
#pragma unroll
  for (int j = 0; j < JT; ++j) o[j * NTHREADS] = acc[j];
}

extern "C" void kernel_launch(void* const* d_in, const int* in_sizes, int n_in,
                              void* d_out, int out_size, void* d_ws, size_t ws_size,
                              hipStream_t stream) {
  const float* log_dt     = (const float*)d_in[0];
  const float* Cri        = (const float*)d_in[1];
  const float* log_A_real = (const float*)d_in[2];
  const float* A_imag     = (const float*)d_in[3];
  float* out = (float*)d_out;
  const int H = in_sizes[0];

  float2* ws2 = (float2*)d_ws;   // 8 MB P/Q + 4 MB A2T

  s4d_prep_kernel<<<dim3(H * N2 / 256), dim3(256), 0, stream>>>(
      log_dt, Cri, log_A_real, A_imag, ws2);
  s4d_main_kernel<<<dim3(H, 2), dim3(NTHREADS), 0, stream>>>(ws2, out);
}

// Round 6
// 77.946 us; speedup vs baseline: 2.0403x; 1.1787x over previous
//
#include <hip/hip_runtime.h>
#include <math.h>

// S4D kernel generation: K[h,l] = 2*Re( sum_n Ck[h,n] * exp(dtA[h,n]*l) )
// H=1024, N2=32, L=4096. Output (H,L) fp32.
//
// Single fused kernel, one block per h, 256 threads, t -> (a=t>>4, b=t&15),
// l = 256*j + 16*a + b.
//   Step 1 (lanes 0-31):  fp64 discretization per mode n: w=exp(dtA),
//          Ck=2*Cc*(w-1)/A, w^16 and w^256 by squaring; -> LDS (f32).
//   Step 2 (lanes 0-63):  P[a][n]=(w^16)^a, Q[b][n]=Ck*w^b tables in LDS,
//          TRANSPOSED layout so writes are 32-consecutive (conflict-free)
//          and step-3 reads are broadcast groups (free).
//   Step 3 (all):  B[n] = P[a][n]*Q[b][n];  s_j = Re(B*W^j) via the stable
//          real recurrence s_j = p*s_{j-1} - q*s_{j-2} (p=2Re(W), q=|W|^2,
//          W=w^256): 3 VALU per (n,j), no loads in the chain, no
//          transcendentals, constant acc[] indices (no scratch spills).

#define N2 32
#define L_LEN 4096
#define NTHREADS 256

__global__ __launch_bounds__(NTHREADS, 4) void s4d_fused_kernel(
    const float* __restrict__ log_dt,      // (H,)
    const float* __restrict__ Cri,         // (H, N2, 2)
    const float* __restrict__ log_A_real,  // (H, N2)
    const float* __restrict__ A_imag,      // (H, N2)
    float* __restrict__ out)               // (H, L)
{
  const int h = blockIdx.x;
  const int t = threadIdx.x;
  const int a = t >> 4;
  const int b = t & 15;

  __shared__ float2 s_w[N2], s_w16[N2], s_ck[N2];
  __shared__ float4 s_Wpq[N2];          // (w256r, w256i, p, q)
  __shared__ float2 s_P[16 * N2];       // [a][n]
  __shared__ float2 s_Q[16 * N2];       // [b][n]

  // ---- Step 1: fp64 prep, one lane per mode ----
  if (t < N2) {
    const int n = t;
    const int idx = h * N2 + n;
    const double dt = exp((double)log_dt[h]);
    const double Ar = -exp((double)log_A_real[idx]);
    const double Ai = (double)A_imag[idx];
    const double xr = dt * Ar;
    const double xi = dt * Ai;
    const double ex = exp(xr);
    const double wr = ex * cos(xi);     // w = exp(dtA)
    const double wi = ex * sin(xi);
    // Ck = 2 * Cc * (w-1)/A  via (w-1)*conj(A)/|A|^2
    const double nr = wr - 1.0, ni = wi;
    const double inv = 1.0 / (Ar * Ar + Ai * Ai);
    const double fr = (nr * Ar + ni * Ai) * inv;
    const double fi = (ni * Ar - nr * Ai) * inv;
    const double c0 = (double)Cri[idx * 2 + 0];
    const double c1 = (double)Cri[idx * 2 + 1];
    s_ck[n] = make_float2((float)(2.0 * (c0 * fr - c1 * fi)),
                          (float)(2.0 * (c0 * fi + c1 * fr)));
    s_w[n] = make_float2((float)wr, (float)wi);
    double ar = wr, ai2 = wi;
#pragma unroll
    for (int k = 0; k < 4; ++k) {       // w^16
      const double tr = ar * ar - ai2 * ai2;
      const double ti = 2.0 * ar * ai2;
      ar = tr; ai2 = ti;
    }
    s_w16[n] = make_float2((float)ar, (float)ai2);
#pragma unroll
    for (int k = 0; k < 4; ++k) {       // w^256
      const double tr = ar * ar - ai2 * ai2;
      const double ti = 2.0 * ar * ai2;
      ar = tr; ai2 = ti;
    }
    s_Wpq[n] = make_float4((float)ar, (float)ai2,
                           (float)(2.0 * ar), (float)(ar * ar + ai2 * ai2));
  }
  __syncthreads();

  // ---- Step 2: P/Q tables, transposed layout ----
  if (t < 64) {
    const int n = t & 31;
    if (t < 32) {
      const float2 g = s_w16[n];
      float pr = 1.0f, pi = 0.0f;
#pragma unroll
      for (int aa = 0; aa < 16; ++aa) { // P[aa][n] = (w^16)^aa
        s_P[aa * N2 + n] = make_float2(pr, pi);
        const float tr = fmaf(pr, g.x, -(pi * g.y));
        const float ti = fmaf(pr, g.y, pi * g.x);
        pr = tr; pi = ti;
      }
    } else {
      const float2 w = s_w[n];
      const float2 c = s_ck[n];
      float qr = c.x, qi = c.y;
#pragma unroll
      for (int bb = 0; bb < 16; ++bb) { // Q[bb][n] = Ck * w^bb
        s_Q[bb * N2 + n] = make_float2(qr, qi);
        const float tr = fmaf(qr, w.x, -(qi * w.y));
        const float ti = fmaf(qr, w.y, qi * w.x);
        qr = tr; qi = ti;
      }
    }
  }
  __syncthreads();

  // ---- Step 3: recurrence sweep ----
  float acc[16];
#pragma unroll
  for (int j = 0; j < 16; ++j) acc[j] = 0.0f;

  const float2* Pa = s_P + a * N2;
  const float2* Qb = s_Q + b * N2;

#pragma unroll 2
  for (int n = 0; n < N2; ++n) {
    const float2 P = Pa[n];             // broadcast (4 addrs/wave)
    const float2 Q = Qb[n];             // broadcast (16 addrs/wave)
    const float4 W = s_Wpq[n];          // uniform broadcast
    const float Br = fmaf(P.x, Q.x, -(P.y * Q.y));
    const float Bi = fmaf(P.x, Q.y, P.y * Q.x);
    float s0 = Br;
    float s1 = fmaf(Br, W.x, -(Bi * W.y));
    acc[0] += s0;
    acc[1] += s1;
#pragma unroll
    for (int j = 2; j < 16; ++j) {
      const float s2 = fmaf(W.z, s1, -(W.w * s0));
      acc[j] += s2;
      s0 = s1; s1 = s2;
    }
  }

  float* o = out + (size_t)h * L_LEN + t;  // l = 256*j + t
#pragma unroll
  for (int j = 0; j < 16; ++j) o[j * NTHREADS] = acc[j];
}

extern "C" void kernel_launch(void* const* d_in, const int* in_sizes, int n_in,
                              void* d_out, int out_size, void* d_ws, size_t ws_size,
                              hipStream_t stream) {
  const float* log_dt     = (const float*)d_in[0];
  const float* Cri        = (const float*)d_in[1];
  const float* log_A_real = (const float*)d_in[2];
  const float* A_imag     = (const float*)d_in[3];
  float* out = (float*)d_out;
  const int H = in_sizes[0];

  s4d_fused_kernel<<<dim3(H), dim3(NTHREADS), 0, stream>>>(
      log_dt, Cri, log_A_real, A_imag, out);
}

// Round 7
// 77.372 us; speedup vs baseline: 2.0555x; 1.0074x over previous
//
#include <hip/hip_runtime.h>
#include <math.h>

// S4D kernel generation: K[h,l] = 2*Re( sum_n Ck[h,n] * exp(dtA[h,n]*l) )
// H=1024, N2=32, L=4096. Output (H,L) fp32.
//
// Single fused kernel, one block per h, 256 threads, t -> (a=t>>4, b=t&15),
// l = 256*j + 16*a + b.
//   Step 1 (lanes 0-31):  fp64 discretization per mode n: w=exp(dtA),
//          Ck=2*Cc*(w-1)/A, w^16/w^256 by squaring; -> LDS (f32).
//   Step 2 (lanes 0-63):  P[a][n]=(w^16)^a, Q[b][n]=Ck*w^b tables in LDS
//          (transposed: writes 32-consecutive, reads broadcast).
//   Step 3 (all): modes in PAIRS with packed-f32 math (v_pk_fma_f32 etc.):
//          B[n] = P[a][n]*Q[b][n];  s_j = Re(B*W^j), W=w^256, via the real
//          recurrence s_j = p*s_{j-1} - q*s_{j-2} run on packed pairs:
//          3 VOP3P insts per (pair,j) = 1.5 VALU/mode/j. Packed acc2[16],
//          horizontal add only at the end. W-table holds (Wr,Wi,p,-q) so the
//          chain needs no negations. No transcendentals/fp64/spills in hot
//          path (R4 lesson: all indices compile-time constant).

#define N2 32
#define L_LEN 4096
#define NTHREADS 256

__device__ __forceinline__ float2 pk_fma(float2 a, float2 b, float2 c) {
  float2 d;
  asm("v_pk_fma_f32 %0, %1, %2, %3" : "=v"(d) : "v"(a), "v"(b), "v"(c));
  return d;
}
__device__ __forceinline__ float2 pk_mul(float2 a, float2 b) {
  float2 d;
  asm("v_pk_mul_f32 %0, %1, %2" : "=v"(d) : "v"(a), "v"(b));
  return d;
}
__device__ __forceinline__ float2 pk_add(float2 a, float2 b) {
  float2 d;
  asm("v_pk_add_f32 %0, %1, %2" : "=v"(d) : "v"(a), "v"(b));
  return d;
}

__global__ __launch_bounds__(NTHREADS, 4) void s4d_fused_kernel(
    const float* __restrict__ log_dt,      // (H,)
    const float* __restrict__ Cri,         // (H, N2, 2)
    const float* __restrict__ log_A_real,  // (H, N2)
    const float* __restrict__ A_imag,      // (H, N2)
    float* __restrict__ out)               // (H, L)
{
  const int h = blockIdx.x;
  const int t = threadIdx.x;
  const int a = t >> 4;
  const int b = t & 15;

  __shared__ float2 s_w[N2], s_w16[N2], s_ck[N2];
  __shared__ float4 s_Wpq[N2];          // (Wr, Wi, p, -q), W = w^256
  __shared__ float4 s_P[16 * N2 / 2];   // [a][npair]: (Pr0,Pi0,Pr1,Pi1)
  __shared__ float4 s_Q[16 * N2 / 2];   // [b][npair]

  // ---- Step 1: fp64 prep, one lane per mode ----
  if (t < N2) {
    const int n = t;
    const int idx = h * N2 + n;
    const double dt = exp((double)log_dt[h]);
    const double Ar = -exp((double)log_A_real[idx]);
    const double Ai = (double)A_imag[idx];
    const double xr = dt * Ar;
    const double xi = dt * Ai;
    const double ex = exp(xr);
    const double wr = ex * cos(xi);     // w = exp(dtA)
    const double wi = ex * sin(xi);
    // Ck = 2 * Cc * (w-1)/A  via (w-1)*conj(A)/|A|^2
    const double nr = wr - 1.0, ni = wi;
    const double inv = 1.0 / (Ar * Ar + Ai * Ai);
    const double fr = (nr * Ar + ni * Ai) * inv;
    const double fi = (ni * Ar - nr * Ai) * inv;
    const double c0 = (double)Cri[idx * 2 + 0];
    const double c1 = (double)Cri[idx * 2 + 1];
    s_ck[n] = make_float2((float)(2.0 * (c0 * fr - c1 * fi)),
                          (float)(2.0 * (c0 * fi + c1 * fr)));
    s_w[n] = make_float2((float)wr, (float)wi);
    double ar = wr, ai2 = wi;
#pragma unroll
    for (int k = 0; k < 4; ++k) {       // w^16
      const double tr = ar * ar - ai2 * ai2;
      const double ti = 2.0 * ar * ai2;
      ar = tr; ai2 = ti;
    }
    s_w16[n] = make_float2((float)ar, (float)ai2);
#pragma unroll
    for (int k = 0; k < 4; ++k) {       // w^256
      const double tr = ar * ar - ai2 * ai2;
      const double ti = 2.0 * ar * ai2;
      ar = tr; ai2 = ti;
    }
    s_Wpq[n] = make_float4((float)ar, (float)ai2,
                           (float)(2.0 * ar), (float)(-(ar * ar + ai2 * ai2)));
  }
  __syncthreads();

  // ---- Step 2: P/Q tables (float2 view of the float4 arrays) ----
  if (t < 64) {
    const int n = t & 31;
    if (t < 32) {
      float2* P2 = (float2*)s_P;
      const float2 g = s_w16[n];
      float pr = 1.0f, pi = 0.0f;
#pragma unroll
      for (int aa = 0; aa < 16; ++aa) { // P[aa][n] = (w^16)^aa
        P2[aa * N2 + n] = make_float2(pr, pi);
        const float tr = fmaf(pr, g.x, -(pi * g.y));
        const float ti = fmaf(pr, g.y, pi * g.x);
        pr = tr; pi = ti;
      }
    } else {
      float2* Q2 = (float2*)s_Q;
      const float2 w = s_w[n];
      const float2 c = s_ck[n];
      float qr = c.x, qi = c.y;
#pragma unroll
      for (int bb = 0; bb < 16; ++bb) { // Q[bb][n] = Ck * w^bb
        Q2[bb * N2 + n] = make_float2(qr, qi);
        const float tr = fmaf(qr, w.x, -(qi * w.y));
        const float ti = fmaf(qr, w.y, qi * w.x);
        qr = tr; qi = ti;
      }
    }
  }
  __syncthreads();

  // ---- Step 3: packed-pair recurrence sweep ----
  float2 acc2[16];
#pragma unroll
  for (int j = 0; j < 16; ++j) acc2[j] = make_float2(0.0f, 0.0f);

  const float4* Pa = s_P + a * (N2 / 2);
  const float4* Qb = s_Q + b * (N2 / 2);

#pragma unroll
  for (int np = 0; np < N2 / 2; ++np) {
    const float4 P = Pa[np];            // (Pr0,Pi0,Pr1,Pi1) broadcast groups
    const float4 Q = Qb[np];
    const float4 W0 = s_Wpq[2 * np];    // uniform broadcast
    const float4 W1 = s_Wpq[2 * np + 1];
    // B = P*Q (complex), per mode of the pair
    const float Br0 = fmaf(P.x, Q.x, -(P.y * Q.y));
    const float Bi0 = fmaf(P.x, Q.y, P.y * Q.x);
    const float Br1 = fmaf(P.z, Q.z, -(P.w * Q.w));
    const float Bi1 = fmaf(P.z, Q.w, P.w * Q.z);
    // s0 = Br, s1 = Re(B*W)
    float2 s0p = make_float2(Br0, Br1);
    float2 s1p = make_float2(fmaf(Br0, W0.x, -(Bi0 * W0.y)),
                             fmaf(Br1, W1.x, -(Bi1 * W1.y)));
    const float2 pp  = make_float2(W0.z, W1.z);
    const float2 mqp = make_float2(W0.w, W1.w);   // -q
    acc2[0] = pk_add(acc2[0], s0p);
    acc2[1] = pk_add(acc2[1], s1p);
#pragma unroll
    for (int j = 2; j < 16; ++j) {
      const float2 s2p = pk_fma(pp, s1p, pk_mul(mqp, s0p));
      acc2[j] = pk_add(acc2[j], s2p);
      s0p = s1p; s1p = s2p;
    }
  }

  float* o = out + (size_t)h * L_LEN + t;  // l = 256*j + t
#pragma unroll
  for (int j = 0; j < 16; ++j) o[j * NTHREADS] = acc2[j].x + acc2[j].y;
}

extern "C" void kernel_launch(void* const* d_in, const int* in_sizes, int n_in,
                              void* d_out, int out_size, void* d_ws, size_t ws_size,
                              hipStream_t stream) {
  const float* log_dt     = (const float*)d_in[0];
  const float* Cri        = (const float*)d_in[1];
  const float* log_A_real = (const float*)d_in[2];
  const float* A_imag     = (const float*)d_in[3];
  float* out = (float*)d_out;
  const int H = in_sizes[0];

  s4d_fused_kernel<<<dim3(H), dim3(NTHREADS), 0, stream>>>(
      log_dt, Cri, log_A_real, A_imag, out);
}